// Round 4
// baseline (352.061 us; speedup 1.0000x reference)
//
#include <hip/hip_runtime.h>

#define TLEN 65536
#define XPLEN 65648   /* TLEN + 112 padded length */
#define TO 32769
#define OU_SIZE 50333184   /* 16*32*3*32769 */

typedef __attribute__((ext_vector_type(8))) short short8v;
typedef __attribute__((ext_vector_type(4))) float float4v;

// ---------------- helpers ----------------
__device__ __forceinline__ float fetch_xp(const float* __restrict__ xr, int idx) {
    // xp[idx] for idx in [0, XPLEN) ; xp = symmetric-pad(x, 55 left, 57 right)
    int p = idx - 55;
    p = (p < 0) ? (-1 - p) : p;
    p = (p >= TLEN) ? (2 * TLEN - 1 - p) : p;
    return xr[p];
}

__device__ __forceinline__ ushort f2bf(float f) {
    unsigned u = __float_as_uint(f);
    unsigned r = (u + 0x7fffu + ((u >> 16) & 1u)) >> 16;
    return (ushort)r;
}

// ---------------- K1: filters ----------------
__global__ __launch_bounds__(256) void k1_filters(
    const float* __restrict__ m, const float* __restrict__ p,
    const float* __restrict__ sd, const float* __restrict__ kb,
    float* __restrict__ Wout, ushort* __restrict__ Wtb)
{
    __shared__ float knots[32][8];
    __shared__ float yh[2][6][4];
    __shared__ float fv[2][32][112];
    __shared__ float mx[64];
    __shared__ float mv[2][7], pv[2][7];
    int tid = threadIdx.x;
    if (tid < 32) {
        float s = exp2f((float)tid * 0.125f) + sd[tid];
        float cum = 0.f;
        for (int k = 0; k < 7; ++k) {
            float c = fminf(fmaxf(kb[k] * s, 1.f), 105.f);
            knots[tid][k] = cum - 3.f * s;   // exclusive cumsum - (K//2)*scale
            cum += c;
        }
    }
    if (tid < 2) {
        float mean = 0.f;
        for (int k = 1; k <= 5; ++k) mean += m[tid * 7 + k];
        mean *= 0.2f;
        for (int k = 0; k < 7; ++k) {
            float msk = (k == 0 || k == 6) ? 0.f : 1.f;
            mv[tid][k] = (m[tid * 7 + k] - mean) * msk;
            pv[tid][k] = p[tid * 7 + k] * msk;
        }
    }
    __syncthreads();
    if (tid < 12) {
        int i = tid / 6, kk = tid % 6;
        float y0 = mv[i][kk], y1 = mv[i][kk + 1], y2 = pv[i][kk], y3 = pv[i][kk + 1];
        yh[i][kk][0] = y0;
        yh[i][kk][1] = y1;
        yh[i][kk][2] = -3.f * y0 - 2.f * y1 + 3.f * y2 - y3;
        yh[i][kk][3] = 2.f * y0 + y1 - 2.f * y2 + y3;
    }
    __syncthreads();
    for (int idx = tid; idx < 7168; idx += 256) {
        int i = idx / 3584, s = (idx / 112) % 32, fi = idx % 112;
        float xi = -56.f + (float)fi * (112.f / 111.f);
        float val = 0.f;
        for (int kk = 0; kk < 6; ++kk) {
            float x0 = knots[s][kk], x1 = knots[s][kk + 1];
            float xn = (xi - x0) / (x1 - x0);
            if (xn >= 0.f && xn < 1.f) {
                val += ((yh[i][kk][3] * xn + yh[i][kk][2]) * xn + yh[i][kk][1]) * xn + yh[i][kk][0];
            }
        }
        fv[i][s][fi] = val;
    }
    __syncthreads();
    if (tid < 64) {
        int i = tid >> 5, s = tid & 31;
        float mm_ = -1e30f;
        for (int fi = 0; fi < 112; ++fi) mm_ = fmaxf(mm_, fv[i][s][fi]);
        mx[tid] = mm_;
    }
    __syncthreads();
    for (int idx = tid; idx < 7168; idx += 256) {
        int i = idx / 3584, s = (idx / 112) % 32, fi = idx % 112;
        int o = i * 32 + s;
        Wout[fi * 64 + o] = fv[i][s][fi] / mx[o];   // layout W[k][o] (f32, for A)
    }
    for (int idx = tid; idx < 8192; idx += 256) {
        int o = idx >> 7, k = idx & 127;
        float val = (k < 112) ? fv[o >> 5][o & 31][k] / mx[o] : 0.f;
        Wtb[idx] = f2bf(val);                      // layout Wt[o][k] bf16, K padded to 128
    }
}

// ---------------- K1b: A[j][k] = sum_o W[j,o] W[k,o] ----------------
__global__ __launch_bounds__(256) void k1b_A(const float* __restrict__ W, float* __restrict__ A)
{
    int idx = blockIdx.x * 256 + threadIdx.x;
    if (idx >= 12544) return;
    int j = idx / 112, k = idx % 112;
    float s = 0.f;
    for (int o = 0; o < 64; ++o) s += W[j * 64 + o] * W[k * 64 + o];
    A[idx] = s;
}

// ---------------- K1c: C[q][dd] ----------------
__global__ __launch_bounds__(256) void k1c_C(const float* __restrict__ A, float* __restrict__ C)
{
    int idx = blockIdx.x * 256 + threadIdx.x;
    if (idx >= 448) return;
    int q = idx / 224, dd = idx % 224;
    int d = dd - 111;
    float s = 0.f;
    for (int k = q; k < 112; k += 2) {
        int jj = k + d;
        if (jj >= 0 && jj < 112) s += A[jj * 112 + k];
    }
    C[idx] = s;
}

// ---------------- K2: MFMA conv + in-register modulus + pooling ----------------
__global__ __launch_bounds__(256) void k2_fwd(
    const float* __restrict__ x, const ushort* __restrict__ Wtb,
    float* __restrict__ out_u, float* __restrict__ out_s)
{
    __shared__ __align__(16) ushort xraw[384];   // bf16 window xp[2*t0 .. 2*t0+383]
    __shared__ float pb[32][33];                 // pooled values [sc][tp_local]
    int row = blockIdx.y;                 // n = b*3 + c
    int b = row / 3, c = row % 3;
    int t0 = blockIdx.x * 128;
    const float* xr = x + row * TLEN;
    int tid = threadIdx.x;

    for (int i = tid; i < 384; i += 256) {
        int idx = 2 * t0 + i;
        float v = (idx < XPLEN) ? fetch_xp(xr, idx) : 0.f;
        xraw[i] = f2bf(v);
    }
    __syncthreads();

    int l = tid & 63, w = tid >> 6;
    int r16 = l & 15, kg = l >> 4;

    float4v acc[2][4];
#pragma unroll
    for (int mt = 0; mt < 2; ++mt)
#pragma unroll
        for (int n = 0; n < 4; ++n)
            acc[mt][n] = (float4v){0.f, 0.f, 0.f, 0.f};

    const ushort* WB = Wtb + r16 * 128 + 8 * kg;
    int ebase = 2 * (32 * w + r16) + 8 * kg;

    union U8 { short8v v; uint u[4]; uint4 q; };

#pragma unroll
    for (int ks = 0; ks < 4; ++ks) {
        U8 a0, a1;
        int e0 = ebase + 32 * ks;
#pragma unroll
        for (int q = 0; q < 4; ++q) {
            a0.u[q] = *(const uint*)&xraw[e0 + 2 * q];        // mt=0 (t .. t+15)
            a1.u[q] = *(const uint*)&xraw[e0 + 32 + 2 * q];   // mt=1 (t+16 ..)
        }
#pragma unroll
        for (int n = 0; n < 4; ++n) {
            U8 bb;
            bb.q = *(const uint4*)(WB + n * 16 * 128 + 32 * ks);
            acc[0][n] = __builtin_amdgcn_mfma_f32_16x16x32_bf16(a0.v, bb.v, acc[0][n], 0, 0, 0);
            acc[1][n] = __builtin_amdgcn_mfma_f32_16x16x32_bf16(a1.v, bb.v, acc[1][n], 0, 0, 0);
        }
    }

    // lane holds: col o = n*16 + r16, rows t = ts + r ; re/im pairs (n=0,n=2) and (n=1,n=3)
#pragma unroll
    for (int mt = 0; mt < 2; ++mt) {
        int ts = t0 + 32 * w + 16 * mt + 4 * kg;
        float u1[4], u2[4];
#pragma unroll
        for (int r = 0; r < 4; ++r) {
            float re1 = acc[mt][0][r], im1 = acc[mt][2][r];
            float re2 = acc[mt][1][r], im2 = acc[mt][3][r];
            u1[r] = sqrtf(re1 * re1 + im1 * im1);
            u2[r] = sqrtf(re2 * re2 + im2 * im2);
        }
        size_t o1 = ((size_t)((b * 32 + r16) * 3 + c)) * TO + ts;
        size_t o2 = ((size_t)((b * 32 + r16 + 16) * 3 + c)) * TO + ts;
#pragma unroll
        for (int r = 0; r < 4; ++r) {
            if (ts + r < TO) {
                out_u[o1 + r] = u1[r];
                out_u[o2 + r] = u2[r];
            }
        }
        if (ts + 3 < TO) {
            pb[r16][8 * w + 4 * mt + kg]      = (u1[0] + u1[1] + u1[2] + u1[3]) * 0.25f;
            pb[r16 + 16][8 * w + 4 * mt + kg] = (u2[0] + u2[1] + u2[2] + u2[3]) * 0.25f;
        }
    }
    __syncthreads();

    int tp0 = t0 >> 2;
    for (int i = tid; i < 1024; i += 256) {
        int sc = i >> 5, tpl = i & 31;
        if (tp0 + tpl < 8192)
            out_s[((size_t)(row * 32 + sc)) * 8192 + tp0 + tpl] = pb[sc][tpl];
    }
}

// ---------------- K3: interior inverse + loss (C in LDS, no atomics) ----------------
__global__ __launch_bounds__(256) void k3_interior(
    const float* __restrict__ x, const float* __restrict__ C,
    double* __restrict__ part)
{
    __shared__ __align__(16) float sx[1248];
    __shared__ __align__(16) float Cl[448];
    __shared__ double wred[4];
    int row = blockIdx.y;
    int s0 = 56 + blockIdx.x * 1024;
    const float* xr = x + row * TLEN;
    int tid = threadIdx.x;
    for (int li = tid; li < 1248; li += 256) {
        int pp = s0 - 111 + li;
        pp = (pp < 0) ? (-1 - pp) : pp;
        pp = (pp >= TLEN) ? (2 * TLEN - 1 - pp) : pp;
        sx[li] = xr[pp];
    }
    for (int li = tid; li < 448; li += 256) Cl[li] = C[li];
    __syncthreads();

    int qe = (55 + s0) & 1;
    const float* Ce = Cl + qe * 224;
    const float* Co = Cl + (qe ^ 1) * 224;
    int base = tid * 4;
    float a0 = 0.f, a1 = 0.f, a2 = 0.f, a3 = 0.f;
    float4 cur = *(const float4*)&sx[base];
#pragma unroll 4
    for (int d4 = 0; d4 < 56; ++d4) {
        float4 nxt = *(const float4*)&sx[base + 4 * d4 + 4];
        float4 cev = *(const float4*)&Ce[4 * d4];     // LDS broadcast
        float4 cov = *(const float4*)&Co[4 * d4];     // LDS broadcast
        a0 = fmaf(cur.x, cev.x, a0); a1 = fmaf(cur.y, cov.x, a1); a2 = fmaf(cur.z, cev.x, a2); a3 = fmaf(cur.w, cov.x, a3);
        a0 = fmaf(cur.y, cev.y, a0); a1 = fmaf(cur.z, cov.y, a1); a2 = fmaf(cur.w, cev.y, a2); a3 = fmaf(nxt.x, cov.y, a3);
        a0 = fmaf(cur.z, cev.z, a0); a1 = fmaf(cur.w, cov.z, a1); a2 = fmaf(nxt.x, cev.z, a2); a3 = fmaf(nxt.y, cov.z, a3);
        a0 = fmaf(cur.w, cev.w, a0); a1 = fmaf(nxt.x, cov.w, a1); a2 = fmaf(nxt.y, cev.w, a2); a3 = fmaf(nxt.z, cov.w, a3);
        cur = nxt;
    }

    int sb = s0 + base;
    double lsum = 0.0;
    if (sb + 0 <= 65478) { float d = a0 - sx[base + 111]; lsum += (double)d * d; }
    if (sb + 1 <= 65478) { float d = a1 - sx[base + 112]; lsum += (double)d * d; }
    if (sb + 2 <= 65478) { float d = a2 - sx[base + 113]; lsum += (double)d * d; }
    if (sb + 3 <= 65478) { float d = a3 - sx[base + 114]; lsum += (double)d * d; }
    for (int off = 32; off > 0; off >>= 1) lsum += __shfl_down(lsum, off, 64);
    int w = tid >> 6;
    if ((tid & 63) == 0) wred[w] = lsum;
    __syncthreads();
    if (tid == 0)
        part[row * 64 + blockIdx.x] = wred[0] + wred[1] + wred[2] + wred[3];
}

// ---------------- K4: edge g_xp evals + edge loss partials (no atomics) ----------------
__global__ __launch_bounds__(256) void k4_edge(
    const float* __restrict__ x, const float* __restrict__ A,
    double* __restrict__ part2)
{
    __shared__ float Al[112][113];
    __shared__ float xpw[240];
    __shared__ double wacc[4];
    int row = blockIdx.x >> 1;
    int side = blockIdx.x & 1;
    const float* xr = x + row * TLEN;
    int tid = threadIdx.x;

    for (int idx = tid; idx < 12544; idx += 256)
        Al[idx / 112][idx % 112] = A[idx];
    {
        int n_x = side ? 225 : 222;
        int woff0 = side ? 65423 : 0;
        if (tid < n_x) xpw[tid] = fetch_xp(xr, woff0 + tid);
    }
    __syncthreads();

    int w = tid >> 6, lane = tid & 63;
    int nS = side ? 57 : 56;
    int woff = side ? 65423 : 0;
    double lacc = 0.0;
    for (int s = w; s < nS; s += 4) {
        float part = 0.f;
#pragma unroll
        for (int half = 0; half < 2; ++half) {
            int i;
            bool has;
            if (!side) { i = half ? (54 - s) : (55 + s); has = half ? (s <= 54) : true; }
            else       { i = half ? (65647 - s) : (65534 + s); has = true; }
            if (has) {
                int klo = max(0, i - 65536);
                int khi = min(111, i);
                int k0 = klo + ((klo ^ i) & 1);
                for (int k = k0; k <= khi; k += 2) {
                    int bi = i - k - woff;
                    part = fmaf(xpw[bi + lane], Al[lane][k], part);
                    if (lane < 48)
                        part = fmaf(xpw[bi + 64 + lane], Al[lane + 64][k], part);
                }
            }
        }
        for (int off = 32; off > 0; off >>= 1) part += __shfl_down(part, off, 64);
        if (lane == 0) {
            float xs = xpw[side ? (111 + s) : (s + 55)];
            float diff = part - xs;
            lacc += (double)diff * diff;
        }
    }
    if (lane == 0) wacc[w] = lacc;
    __syncthreads();
    if (tid == 0) part2[blockIdx.x] = wacc[0] + wacc[1] + wacc[2] + wacc[3];
}

// ---------------- K5: final reduction ----------------
__global__ __launch_bounds__(256) void k5_final(
    const double* __restrict__ part, const double* __restrict__ part2,
    float* __restrict__ out_loss)
{
    __shared__ double red[256];
    double acc = 0.0;
    for (int idx = threadIdx.x; idx < 3072; idx += 256) acc += part[idx];
    if (threadIdx.x < 96) acc += part2[threadIdx.x];
    red[threadIdx.x] = acc;
    __syncthreads();
    for (int st = 128; st > 0; st >>= 1) {
        if (threadIdx.x < st) red[threadIdx.x] += red[threadIdx.x + st];
        __syncthreads();
    }
    if (threadIdx.x == 0)
        out_loss[0] = (float)(red[0] / 3145728.0);
}

// ---------------- launch ----------------
extern "C" void kernel_launch(void* const* d_in, const int* in_sizes, int n_in,
                              void* d_out, int out_size, void* d_ws, size_t ws_size,
                              hipStream_t stream)
{
    (void)in_sizes; (void)n_in; (void)ws_size;
    const float* x  = (const float*)d_in[0];
    const float* m  = (const float*)d_in[1];
    const float* p  = (const float*)d_in[2];
    const float* sd = (const float*)d_in[3];
    const float* kb = (const float*)d_in[4];
    float* out = (float*)d_out;
    float* ws  = (float*)d_ws;

    float* ws_w     = ws;            // 7168 : W[k][o] f32
    float* ws_C     = ws + 7168;     // 448  : C[q][224]
    float* ws_A     = ws + 7616;     // 12544: A[j][k] -> ends 20160
    double* ws_part  = (double*)(ws + 20160); // 3072 doubles -> ends 26304
    double* ws_part2 = (double*)(ws + 26304); // 96 doubles   -> ends 26496
    ushort* ws_wtb  = (ushort*)(ws + 26496);  // 8192 ushort: Wt[o][k] bf16 padded

    k1_filters<<<1, 256, 0, stream>>>(m, p, sd, kb, ws_w, ws_wtb);
    k1b_A<<<49, 256, 0, stream>>>(ws_w, ws_A);
    k1c_C<<<2, 256, 0, stream>>>(ws_A, ws_C);
    k2_fwd<<<dim3(257, 48), 256, 0, stream>>>(x, ws_wtb, out, out + OU_SIZE);
    k3_interior<<<dim3(64, 48), 256, 0, stream>>>(x, ws_C, ws_part);
    k4_edge<<<96, 256, 0, stream>>>(x, ws_A, ws_part2);
    k5_final<<<1, 256, 0, stream>>>(ws_part, ws_part2, out + (out_size - 1));
}

// Round 5
// 320.836 us; speedup vs baseline: 1.0973x; 1.0973x over previous
//
#include <hip/hip_runtime.h>

#define TLEN 65536
#define XPLEN 65648   /* TLEN + 112 padded length */
#define TO 32769
#define OU_SIZE 50333184   /* 16*32*3*32769 */

typedef __attribute__((ext_vector_type(8))) short short8v;
typedef __attribute__((ext_vector_type(4))) float float4v;

// ---------------- helpers ----------------
__device__ __forceinline__ float fetch_xp(const float* __restrict__ xr, int idx) {
    // xp[idx] for idx in [0, XPLEN) ; xp = symmetric-pad(x, 55 left, 57 right)
    int p = idx - 55;
    p = (p < 0) ? (-1 - p) : p;
    p = (p >= TLEN) ? (2 * TLEN - 1 - p) : p;
    return xr[p];
}

__device__ __forceinline__ ushort f2bf(float f) {
    unsigned u = __float_as_uint(f);
    unsigned r = (u + 0x7fffu + ((u >> 16) & 1u)) >> 16;
    return (ushort)r;
}

// ---------------- K1: filters ----------------
__global__ __launch_bounds__(256) void k1_filters(
    const float* __restrict__ m, const float* __restrict__ p,
    const float* __restrict__ sd, const float* __restrict__ kb,
    float* __restrict__ Wout, ushort* __restrict__ Wtb)
{
    __shared__ float knots[32][8];
    __shared__ float yh[2][6][4];
    __shared__ float fv[2][32][112];
    __shared__ float mx[64];
    __shared__ float mv[2][7], pv[2][7];
    int tid = threadIdx.x;
    if (tid < 32) {
        float s = exp2f((float)tid * 0.125f) + sd[tid];
        float cum = 0.f;
        for (int k = 0; k < 7; ++k) {
            float c = fminf(fmaxf(kb[k] * s, 1.f), 105.f);
            knots[tid][k] = cum - 3.f * s;   // exclusive cumsum - (K//2)*scale
            cum += c;
        }
    }
    if (tid < 2) {
        float mean = 0.f;
        for (int k = 1; k <= 5; ++k) mean += m[tid * 7 + k];
        mean *= 0.2f;
        for (int k = 0; k < 7; ++k) {
            float msk = (k == 0 || k == 6) ? 0.f : 1.f;
            mv[tid][k] = (m[tid * 7 + k] - mean) * msk;
            pv[tid][k] = p[tid * 7 + k] * msk;
        }
    }
    __syncthreads();
    if (tid < 12) {
        int i = tid / 6, kk = tid % 6;
        float y0 = mv[i][kk], y1 = mv[i][kk + 1], y2 = pv[i][kk], y3 = pv[i][kk + 1];
        yh[i][kk][0] = y0;
        yh[i][kk][1] = y1;
        yh[i][kk][2] = -3.f * y0 - 2.f * y1 + 3.f * y2 - y3;
        yh[i][kk][3] = 2.f * y0 + y1 - 2.f * y2 + y3;
    }
    __syncthreads();
    for (int idx = tid; idx < 7168; idx += 256) {
        int i = idx / 3584, s = (idx / 112) % 32, fi = idx % 112;
        float xi = -56.f + (float)fi * (112.f / 111.f);
        float val = 0.f;
        for (int kk = 0; kk < 6; ++kk) {
            float x0 = knots[s][kk], x1 = knots[s][kk + 1];
            float xn = (xi - x0) / (x1 - x0);
            if (xn >= 0.f && xn < 1.f) {
                val += ((yh[i][kk][3] * xn + yh[i][kk][2]) * xn + yh[i][kk][1]) * xn + yh[i][kk][0];
            }
        }
        fv[i][s][fi] = val;
    }
    __syncthreads();
    if (tid < 64) {
        int i = tid >> 5, s = tid & 31;
        float mm_ = -1e30f;
        for (int fi = 0; fi < 112; ++fi) mm_ = fmaxf(mm_, fv[i][s][fi]);
        mx[tid] = mm_;
    }
    __syncthreads();
    for (int idx = tid; idx < 7168; idx += 256) {
        int i = idx / 3584, s = (idx / 112) % 32, fi = idx % 112;
        int o = i * 32 + s;
        Wout[fi * 64 + o] = fv[i][s][fi] / mx[o];   // layout W[k][o] (f32, for A)
    }
    for (int idx = tid; idx < 8192; idx += 256) {
        int o = idx >> 7, k = idx & 127;
        float val = (k < 112) ? fv[o >> 5][o & 31][k] / mx[o] : 0.f;
        Wtb[idx] = f2bf(val);                      // layout Wt[o][k] bf16, K padded to 128
    }
}

// ---------------- K1b: A[j][k] = sum_o W[j,o] W[k,o] ----------------
__global__ __launch_bounds__(256) void k1b_A(const float* __restrict__ W, float* __restrict__ A)
{
    int idx = blockIdx.x * 256 + threadIdx.x;
    if (idx >= 12544) return;
    int j = idx / 112, k = idx % 112;
    float s = 0.f;
    for (int o = 0; o < 64; ++o) s += W[j * 64 + o] * W[k * 64 + o];
    A[idx] = s;
}

// ---------------- K1c: C[q][dd] ----------------
__global__ __launch_bounds__(256) void k1c_C(const float* __restrict__ A, float* __restrict__ C)
{
    int idx = blockIdx.x * 256 + threadIdx.x;
    if (idx >= 448) return;
    int q = idx / 224, dd = idx % 224;
    int d = dd - 111;
    float s = 0.f;
    for (int k = q; k < 112; k += 2) {
        int jj = k + d;
        if (jj >= 0 && jj < 112) s += A[jj * 112 + k];
    }
    C[idx] = s;
}

// ---------------- K2: persistent-W MFMA conv + in-register modulus + pooling ----------------
__global__ __launch_bounds__(256) void k2_fwd(
    const float* __restrict__ x, const ushort* __restrict__ Wtb,
    float* __restrict__ out_u, float* __restrict__ out_s)
{
    __shared__ __align__(16) ushort xraw[384];   // bf16 window xp[2*t0 .. 2*t0+383]
    __shared__ float pb[32][33];                 // pooled values [sc][tp_local]
    int row = blockIdx.y;                 // n = b*3 + c
    int b = row / 3, c = row % 3;
    const float* xr = x + row * TLEN;
    int tid = threadIdx.x;
    int l = tid & 63, w = tid >> 6;
    int r16 = l & 15, kg = l >> 4;

    union U8 { short8v v; uint u[4]; uint4 q; };

    // hoist all B-operand fragments into registers once per block (16 KB table)
    const ushort* WB = Wtb + r16 * 128 + 8 * kg;
    U8 wreg[4][4];
#pragma unroll
    for (int n = 0; n < 4; ++n)
#pragma unroll
        for (int ks = 0; ks < 4; ++ks)
            wreg[n][ks].q = *(const uint4*)(WB + n * 2048 + 32 * ks);

    int ebase = 2 * (32 * w + r16) + 8 * kg;

    for (int tile = blockIdx.x; tile < 257; tile += 16) {
        int t0 = tile * 128;

        __syncthreads();   // previous iteration's pb consumers done before re-staging
        for (int i = tid; i < 384; i += 256) {
            int idx = 2 * t0 + i;
            float v = (idx < XPLEN) ? fetch_xp(xr, idx) : 0.f;
            xraw[i] = f2bf(v);
        }
        __syncthreads();

        float4v acc[2][4];
#pragma unroll
        for (int mt = 0; mt < 2; ++mt)
#pragma unroll
            for (int n = 0; n < 4; ++n)
                acc[mt][n] = (float4v){0.f, 0.f, 0.f, 0.f};

#pragma unroll
        for (int ks = 0; ks < 4; ++ks) {
            U8 a0, a1;
            int e0 = ebase + 32 * ks;
#pragma unroll
            for (int q = 0; q < 4; ++q) {
                a0.u[q] = *(const uint*)&xraw[e0 + 2 * q];        // mt=0 (t .. t+15)
                a1.u[q] = *(const uint*)&xraw[e0 + 32 + 2 * q];   // mt=1 (t+16 ..)
            }
#pragma unroll
            for (int n = 0; n < 4; ++n) {
                acc[0][n] = __builtin_amdgcn_mfma_f32_16x16x32_bf16(a0.v, wreg[n][ks].v, acc[0][n], 0, 0, 0);
                acc[1][n] = __builtin_amdgcn_mfma_f32_16x16x32_bf16(a1.v, wreg[n][ks].v, acc[1][n], 0, 0, 0);
            }
        }

        // lane holds: col o = n*16 + r16, rows t = ts + r ; re/im pairs (n=0,n=2) and (n=1,n=3)
#pragma unroll
        for (int mt = 0; mt < 2; ++mt) {
            int ts = t0 + 32 * w + 16 * mt + 4 * kg;
            float u1[4], u2[4];
#pragma unroll
            for (int r = 0; r < 4; ++r) {
                float re1 = acc[mt][0][r], im1 = acc[mt][2][r];
                float re2 = acc[mt][1][r], im2 = acc[mt][3][r];
                u1[r] = sqrtf(re1 * re1 + im1 * im1);
                u2[r] = sqrtf(re2 * re2 + im2 * im2);
            }
            size_t o1 = ((size_t)((b * 32 + r16) * 3 + c)) * TO + ts;
            size_t o2 = ((size_t)((b * 32 + r16 + 16) * 3 + c)) * TO + ts;
#pragma unroll
            for (int r = 0; r < 4; ++r) {
                if (ts + r < TO) {
                    out_u[o1 + r] = u1[r];
                    out_u[o2 + r] = u2[r];
                }
            }
            if (ts + 3 < TO) {
                pb[r16][8 * w + 4 * mt + kg]      = (u1[0] + u1[1] + u1[2] + u1[3]) * 0.25f;
                pb[r16 + 16][8 * w + 4 * mt + kg] = (u2[0] + u2[1] + u2[2] + u2[3]) * 0.25f;
            }
        }
        __syncthreads();

        int tp0 = t0 >> 2;
        for (int i = tid; i < 1024; i += 256) {
            int sc = i >> 5, tpl = i & 31;
            if (tp0 + tpl < 8192)
                out_s[((size_t)(row * 32 + sc)) * 8192 + tp0 + tpl] = pb[sc][tpl];
        }
    }
}

// ---------------- K3: interior inverse + loss (C in LDS, no atomics) ----------------
__global__ __launch_bounds__(256) void k3_interior(
    const float* __restrict__ x, const float* __restrict__ C,
    double* __restrict__ part)
{
    __shared__ __align__(16) float sx[1248];
    __shared__ __align__(16) float Cl[448];
    __shared__ double wred[4];
    int row = blockIdx.y;
    int s0 = 56 + blockIdx.x * 1024;
    const float* xr = x + row * TLEN;
    int tid = threadIdx.x;
    for (int li = tid; li < 1248; li += 256) {
        int pp = s0 - 111 + li;
        pp = (pp < 0) ? (-1 - pp) : pp;
        pp = (pp >= TLEN) ? (2 * TLEN - 1 - pp) : pp;
        sx[li] = xr[pp];
    }
    for (int li = tid; li < 448; li += 256) Cl[li] = C[li];
    __syncthreads();

    int qe = (55 + s0) & 1;
    const float* Ce = Cl + qe * 224;
    const float* Co = Cl + (qe ^ 1) * 224;
    int base = tid * 4;
    float a0 = 0.f, a1 = 0.f, a2 = 0.f, a3 = 0.f;
    float4 cur = *(const float4*)&sx[base];
#pragma unroll 4
    for (int d4 = 0; d4 < 56; ++d4) {
        float4 nxt = *(const float4*)&sx[base + 4 * d4 + 4];
        float4 cev = *(const float4*)&Ce[4 * d4];     // LDS broadcast
        float4 cov = *(const float4*)&Co[4 * d4];     // LDS broadcast
        a0 = fmaf(cur.x, cev.x, a0); a1 = fmaf(cur.y, cov.x, a1); a2 = fmaf(cur.z, cev.x, a2); a3 = fmaf(cur.w, cov.x, a3);
        a0 = fmaf(cur.y, cev.y, a0); a1 = fmaf(cur.z, cov.y, a1); a2 = fmaf(cur.w, cev.y, a2); a3 = fmaf(nxt.x, cov.y, a3);
        a0 = fmaf(cur.z, cev.z, a0); a1 = fmaf(cur.w, cov.z, a1); a2 = fmaf(nxt.x, cev.z, a2); a3 = fmaf(nxt.y, cov.z, a3);
        a0 = fmaf(cur.w, cev.w, a0); a1 = fmaf(nxt.x, cov.w, a1); a2 = fmaf(nxt.y, cev.w, a2); a3 = fmaf(nxt.z, cov.w, a3);
        cur = nxt;
    }

    int sb = s0 + base;
    double lsum = 0.0;
    if (sb + 0 <= 65478) { float d = a0 - sx[base + 111]; lsum += (double)d * d; }
    if (sb + 1 <= 65478) { float d = a1 - sx[base + 112]; lsum += (double)d * d; }
    if (sb + 2 <= 65478) { float d = a2 - sx[base + 113]; lsum += (double)d * d; }
    if (sb + 3 <= 65478) { float d = a3 - sx[base + 114]; lsum += (double)d * d; }
    for (int off = 32; off > 0; off >>= 1) lsum += __shfl_down(lsum, off, 64);
    int w = tid >> 6;
    if ((tid & 63) == 0) wred[w] = lsum;
    __syncthreads();
    if (tid == 0)
        part[row * 64 + blockIdx.x] = wred[0] + wred[1] + wred[2] + wred[3];
}

// ---------------- K4: edge g_xp evals + edge loss partials (no atomics) ----------------
__global__ __launch_bounds__(256) void k4_edge(
    const float* __restrict__ x, const float* __restrict__ A,
    double* __restrict__ part2)
{
    __shared__ float Al[112][113];
    __shared__ float xpw[240];
    __shared__ double wacc[4];
    int row = blockIdx.x >> 1;
    int side = blockIdx.x & 1;
    const float* xr = x + row * TLEN;
    int tid = threadIdx.x;

    for (int idx = tid; idx < 12544; idx += 256)
        Al[idx / 112][idx % 112] = A[idx];
    {
        int n_x = side ? 225 : 222;
        int woff0 = side ? 65423 : 0;
        if (tid < n_x) xpw[tid] = fetch_xp(xr, woff0 + tid);
    }
    __syncthreads();

    int w = tid >> 6, lane = tid & 63;
    int nS = side ? 57 : 56;
    int woff = side ? 65423 : 0;
    double lacc = 0.0;
    for (int s = w; s < nS; s += 4) {
        float part = 0.f;
#pragma unroll
        for (int half = 0; half < 2; ++half) {
            int i;
            bool has;
            if (!side) { i = half ? (54 - s) : (55 + s); has = half ? (s <= 54) : true; }
            else       { i = half ? (65647 - s) : (65534 + s); has = true; }
            if (has) {
                int klo = max(0, i - 65536);
                int khi = min(111, i);
                int k0 = klo + ((klo ^ i) & 1);
                for (int k = k0; k <= khi; k += 2) {
                    int bi = i - k - woff;
                    part = fmaf(xpw[bi + lane], Al[lane][k], part);
                    if (lane < 48)
                        part = fmaf(xpw[bi + 64 + lane], Al[lane + 64][k], part);
                }
            }
        }
        for (int off = 32; off > 0; off >>= 1) part += __shfl_down(part, off, 64);
        if (lane == 0) {
            float xs = xpw[side ? (111 + s) : (s + 55)];
            float diff = part - xs;
            lacc += (double)diff * diff;
        }
    }
    if (lane == 0) wacc[w] = lacc;
    __syncthreads();
    if (tid == 0) part2[blockIdx.x] = wacc[0] + wacc[1] + wacc[2] + wacc[3];
}

// ---------------- K5: final reduction ----------------
__global__ __launch_bounds__(256) void k5_final(
    const double* __restrict__ part, const double* __restrict__ part2,
    float* __restrict__ out_loss)
{
    __shared__ double red[256];
    double acc = 0.0;
    for (int idx = threadIdx.x; idx < 3072; idx += 256) acc += part[idx];
    if (threadIdx.x < 96) acc += part2[threadIdx.x];
    red[threadIdx.x] = acc;
    __syncthreads();
    for (int st = 128; st > 0; st >>= 1) {
        if (threadIdx.x < st) red[threadIdx.x] += red[threadIdx.x + st];
        __syncthreads();
    }
    if (threadIdx.x == 0)
        out_loss[0] = (float)(red[0] / 3145728.0);
}

// ---------------- launch ----------------
extern "C" void kernel_launch(void* const* d_in, const int* in_sizes, int n_in,
                              void* d_out, int out_size, void* d_ws, size_t ws_size,
                              hipStream_t stream)
{
    (void)in_sizes; (void)n_in; (void)ws_size;
    const float* x  = (const float*)d_in[0];
    const float* m  = (const float*)d_in[1];
    const float* p  = (const float*)d_in[2];
    const float* sd = (const float*)d_in[3];
    const float* kb = (const float*)d_in[4];
    float* out = (float*)d_out;
    float* ws  = (float*)d_ws;

    float* ws_w     = ws;            // 7168 : W[k][o] f32
    float* ws_C     = ws + 7168;     // 448  : C[q][224]
    float* ws_A     = ws + 7616;     // 12544: A[j][k] -> ends 20160
    double* ws_part  = (double*)(ws + 20160); // 3072 doubles -> ends 26304
    double* ws_part2 = (double*)(ws + 26304); // 96 doubles   -> ends 26496
    ushort* ws_wtb  = (ushort*)(ws + 26496);  // 8192 ushort: Wt[o][k] bf16 padded

    k1_filters<<<1, 256, 0, stream>>>(m, p, sd, kb, ws_w, ws_wtb);
    k1b_A<<<49, 256, 0, stream>>>(ws_w, ws_A);
    k1c_C<<<2, 256, 0, stream>>>(ws_A, ws_C);
    k2_fwd<<<dim3(16, 48), 256, 0, stream>>>(x, ws_wtb, out, out + OU_SIZE);
    k3_interior<<<dim3(64, 48), 256, 0, stream>>>(x, ws_C, ws_part);
    k4_edge<<<96, 256, 0, stream>>>(x, ws_A, ws_part2);
    k5_final<<<1, 256, 0, stream>>>(ws_part, ws_part2, out + (out_size - 1));
}

// Round 6
// 312.043 us; speedup vs baseline: 1.1282x; 1.0282x over previous
//
#include <hip/hip_runtime.h>

#define TLEN 65536
#define XPLEN 65648   /* TLEN + 112 padded length */
#define TO 32769
#define OU_SIZE 50333184   /* 16*32*3*32769 */

typedef __attribute__((ext_vector_type(8))) short short8v;
typedef __attribute__((ext_vector_type(4))) float float4v;

// ---------------- helpers ----------------
__device__ __forceinline__ float fetch_xp(const float* __restrict__ xr, int idx) {
    // xp[idx] for idx in [0, XPLEN) ; xp = symmetric-pad(x, 55 left, 57 right)
    int p = idx - 55;
    p = (p < 0) ? (-1 - p) : p;
    p = (p >= TLEN) ? (2 * TLEN - 1 - p) : p;
    return xr[p];
}

__device__ __forceinline__ ushort f2bf(float f) {
    unsigned u = __float_as_uint(f);
    unsigned r = (u + 0x7fffu + ((u >> 16) & 1u)) >> 16;
    return (ushort)r;
}

// ---------------- K1: filters ----------------
__global__ __launch_bounds__(256) void k1_filters(
    const float* __restrict__ m, const float* __restrict__ p,
    const float* __restrict__ sd, const float* __restrict__ kb,
    float* __restrict__ Wout, ushort* __restrict__ Wtb)
{
    __shared__ float knots[32][8];
    __shared__ float yh[2][6][4];
    __shared__ float fv[2][32][112];
    __shared__ float mx[64];
    __shared__ float mv[2][7], pv[2][7];
    int tid = threadIdx.x;
    if (tid < 32) {
        float s = exp2f((float)tid * 0.125f) + sd[tid];
        float cum = 0.f;
        for (int k = 0; k < 7; ++k) {
            float c = fminf(fmaxf(kb[k] * s, 1.f), 105.f);
            knots[tid][k] = cum - 3.f * s;   // exclusive cumsum - (K//2)*scale
            cum += c;
        }
    }
    if (tid < 2) {
        float mean = 0.f;
        for (int k = 1; k <= 5; ++k) mean += m[tid * 7 + k];
        mean *= 0.2f;
        for (int k = 0; k < 7; ++k) {
            float msk = (k == 0 || k == 6) ? 0.f : 1.f;
            mv[tid][k] = (m[tid * 7 + k] - mean) * msk;
            pv[tid][k] = p[tid * 7 + k] * msk;
        }
    }
    __syncthreads();
    if (tid < 12) {
        int i = tid / 6, kk = tid % 6;
        float y0 = mv[i][kk], y1 = mv[i][kk + 1], y2 = pv[i][kk], y3 = pv[i][kk + 1];
        yh[i][kk][0] = y0;
        yh[i][kk][1] = y1;
        yh[i][kk][2] = -3.f * y0 - 2.f * y1 + 3.f * y2 - y3;
        yh[i][kk][3] = 2.f * y0 + y1 - 2.f * y2 + y3;
    }
    __syncthreads();
    for (int idx = tid; idx < 7168; idx += 256) {
        int i = idx / 3584, s = (idx / 112) % 32, fi = idx % 112;
        float xi = -56.f + (float)fi * (112.f / 111.f);
        float val = 0.f;
        for (int kk = 0; kk < 6; ++kk) {
            float x0 = knots[s][kk], x1 = knots[s][kk + 1];
            float xn = (xi - x0) / (x1 - x0);
            if (xn >= 0.f && xn < 1.f) {
                val += ((yh[i][kk][3] * xn + yh[i][kk][2]) * xn + yh[i][kk][1]) * xn + yh[i][kk][0];
            }
        }
        fv[i][s][fi] = val;
    }
    __syncthreads();
    if (tid < 64) {
        int i = tid >> 5, s = tid & 31;
        float mm_ = -1e30f;
        for (int fi = 0; fi < 112; ++fi) mm_ = fmaxf(mm_, fv[i][s][fi]);
        mx[tid] = mm_;
    }
    __syncthreads();
    for (int idx = tid; idx < 7168; idx += 256) {
        int i = idx / 3584, s = (idx / 112) % 32, fi = idx % 112;
        int o = i * 32 + s;
        Wout[fi * 64 + o] = fv[i][s][fi] / mx[o];   // layout W[k][o] (f32, for A)
    }
    for (int idx = tid; idx < 8192; idx += 256) {
        int o = idx >> 7, k = idx & 127;
        float val = (k < 112) ? fv[o >> 5][o & 31][k] / mx[o] : 0.f;
        Wtb[idx] = f2bf(val);                      // layout Wt[o][k] bf16, K padded to 128
    }
}

// ---------------- K1b: A[j][k] = sum_o W[j,o] W[k,o] ----------------
__global__ __launch_bounds__(256) void k1b_A(const float* __restrict__ W, float* __restrict__ A)
{
    int idx = blockIdx.x * 256 + threadIdx.x;
    if (idx >= 12544) return;
    int j = idx / 112, k = idx % 112;
    float s = 0.f;
    for (int o = 0; o < 64; ++o) s += W[j * 64 + o] * W[k * 64 + o];
    A[idx] = s;
}

// ---------------- K1c: C[q][dd] ----------------
__global__ __launch_bounds__(256) void k1c_C(const float* __restrict__ A, float* __restrict__ C)
{
    int idx = blockIdx.x * 256 + threadIdx.x;
    if (idx >= 448) return;
    int q = idx / 224, dd = idx % 224;
    int d = dd - 111;
    float s = 0.f;
    for (int k = q; k < 112; k += 2) {
        int jj = k + d;
        if (jj >= 0 && jj < 112) s += A[jj * 112 + k];
    }
    C[idx] = s;
}

// ---------------- K2: persistent-W MFMA conv + LDS-transposed coalesced stores ----------------
__global__ __launch_bounds__(256) void k2_fwd(
    const float* __restrict__ x, const ushort* __restrict__ Wtb,
    float* __restrict__ out_u, float* __restrict__ out_s)
{
    __shared__ __align__(16) ushort xraw[384];   // bf16 window xp[2*t0 .. 2*t0+383]
    __shared__ float ub[128][33];                // u values [t_local][sc]
    __shared__ float pb[32][33];                 // pooled values [sc][tp_local]
    int row = blockIdx.y;                 // n = b*3 + c
    int b = row / 3, c = row % 3;
    const float* xr = x + row * TLEN;
    int tid = threadIdx.x;
    int l = tid & 63, w = tid >> 6;
    int r16 = l & 15, kg = l >> 4;

    union U8 { short8v v; uint u[4]; uint4 q; };

    // hoist all B-operand fragments into registers once per block (16 KB table)
    const ushort* WB = Wtb + r16 * 128 + 8 * kg;
    U8 wreg[4][4];
#pragma unroll
    for (int n = 0; n < 4; ++n)
#pragma unroll
        for (int ks = 0; ks < 4; ++ks)
            wreg[n][ks].q = *(const uint4*)(WB + n * 2048 + 32 * ks);

    int ebase = 2 * (32 * w + r16) + 8 * kg;

    for (int tile = blockIdx.x; tile < 257; tile += 16) {
        int t0 = tile * 128;

        __syncthreads();   // previous iteration's LDS consumers done before re-staging
        for (int i = tid; i < 384; i += 256) {
            int idx = 2 * t0 + i;
            float v = (idx < XPLEN) ? fetch_xp(xr, idx) : 0.f;
            xraw[i] = f2bf(v);
        }
        __syncthreads();

        float4v acc[2][4];
#pragma unroll
        for (int mt = 0; mt < 2; ++mt)
#pragma unroll
            for (int n = 0; n < 4; ++n)
                acc[mt][n] = (float4v){0.f, 0.f, 0.f, 0.f};

#pragma unroll
        for (int ks = 0; ks < 4; ++ks) {
            U8 a0, a1;
            int e0 = ebase + 32 * ks;
#pragma unroll
            for (int q = 0; q < 4; ++q) {
                a0.u[q] = *(const uint*)&xraw[e0 + 2 * q];        // mt=0 (t .. t+15)
                a1.u[q] = *(const uint*)&xraw[e0 + 32 + 2 * q];   // mt=1 (t+16 ..)
            }
#pragma unroll
            for (int n = 0; n < 4; ++n) {
                acc[0][n] = __builtin_amdgcn_mfma_f32_16x16x32_bf16(a0.v, wreg[n][ks].v, acc[0][n], 0, 0, 0);
                acc[1][n] = __builtin_amdgcn_mfma_f32_16x16x32_bf16(a1.v, wreg[n][ks].v, acc[1][n], 0, 0, 0);
            }
        }

        // lane holds: col o = n*16 + r16, rows t = tl + r ; re/im pairs (n=0,n=2) and (n=1,n=3)
#pragma unroll
        for (int mt = 0; mt < 2; ++mt) {
            int tl = 32 * w + 16 * mt + 4 * kg;
            float u1[4], u2[4];
#pragma unroll
            for (int r = 0; r < 4; ++r) {
                float re1 = acc[mt][0][r], im1 = acc[mt][2][r];
                float re2 = acc[mt][1][r], im2 = acc[mt][3][r];
                u1[r] = sqrtf(re1 * re1 + im1 * im1);
                u2[r] = sqrtf(re2 * re2 + im2 * im2);
            }
#pragma unroll
            for (int r = 0; r < 4; ++r) {
                ub[tl + r][r16]      = u1[r];
                ub[tl + r][r16 + 16] = u2[r];
            }
            pb[r16][tl >> 2]      = (u1[0] + u1[1] + u1[2] + u1[3]) * 0.25f;
            pb[r16 + 16][tl >> 2] = (u2[0] + u2[1] + u2[2] + u2[3]) * 0.25f;
        }
        __syncthreads();

        // coalesced out_u: per iteration, 128 consecutive threads cover 512
        // contiguous bytes of one (b,sc,c) row
        {
            int col = tid & 127;
            int hrow = tid >> 7;             // 0 or 1
            int t = t0 + col;
            bool tok = t < TO;
            size_t base0 = ((size_t)((b * 32) * 3 + c)) * TO + t;
#pragma unroll
            for (int rr = 0; rr < 16; ++rr) {
                int orow = 2 * rr + hrow;
                float v = ub[col][orow];
                if (tok)
                    __builtin_nontemporal_store(v, &out_u[base0 + (size_t)orow * 3 * TO]);
            }
        }

        // coalesced out_s
        int tp0 = t0 >> 2;
#pragma unroll
        for (int rr = 0; rr < 4; ++rr) {
            int s2 = rr * 256 + tid;
            int orow = s2 >> 5, tpl = s2 & 31;
            if (tp0 + tpl < 8192)
                __builtin_nontemporal_store(pb[orow][tpl],
                    &out_s[((size_t)(row * 32 + orow)) * 8192 + tp0 + tpl]);
        }
    }
}

// ---------------- K3: interior inverse + loss (C in LDS, no atomics) ----------------
__global__ __launch_bounds__(256) void k3_interior(
    const float* __restrict__ x, const float* __restrict__ C,
    double* __restrict__ part)
{
    __shared__ __align__(16) float sx[1248];
    __shared__ __align__(16) float Cl[448];
    __shared__ double wred[4];
    int row = blockIdx.y;
    int s0 = 56 + blockIdx.x * 1024;
    const float* xr = x + row * TLEN;
    int tid = threadIdx.x;
    for (int li = tid; li < 1248; li += 256) {
        int pp = s0 - 111 + li;
        pp = (pp < 0) ? (-1 - pp) : pp;
        pp = (pp >= TLEN) ? (2 * TLEN - 1 - pp) : pp;
        sx[li] = xr[pp];
    }
    for (int li = tid; li < 448; li += 256) Cl[li] = C[li];
    __syncthreads();

    int qe = (55 + s0) & 1;
    const float* Ce = Cl + qe * 224;
    const float* Co = Cl + (qe ^ 1) * 224;
    int base = tid * 4;
    float a0 = 0.f, a1 = 0.f, a2 = 0.f, a3 = 0.f;
    float4 cur = *(const float4*)&sx[base];
#pragma unroll 4
    for (int d4 = 0; d4 < 56; ++d4) {
        float4 nxt = *(const float4*)&sx[base + 4 * d4 + 4];
        float4 cev = *(const float4*)&Ce[4 * d4];     // LDS broadcast
        float4 cov = *(const float4*)&Co[4 * d4];     // LDS broadcast
        a0 = fmaf(cur.x, cev.x, a0); a1 = fmaf(cur.y, cov.x, a1); a2 = fmaf(cur.z, cev.x, a2); a3 = fmaf(cur.w, cov.x, a3);
        a0 = fmaf(cur.y, cev.y, a0); a1 = fmaf(cur.z, cov.y, a1); a2 = fmaf(cur.w, cev.y, a2); a3 = fmaf(nxt.x, cov.y, a3);
        a0 = fmaf(cur.z, cev.z, a0); a1 = fmaf(cur.w, cov.z, a1); a2 = fmaf(nxt.x, cev.z, a2); a3 = fmaf(nxt.y, cov.z, a3);
        a0 = fmaf(cur.w, cev.w, a0); a1 = fmaf(nxt.x, cov.w, a1); a2 = fmaf(nxt.y, cev.w, a2); a3 = fmaf(nxt.z, cov.w, a3);
        cur = nxt;
    }

    int sb = s0 + base;
    double lsum = 0.0;
    if (sb + 0 <= 65478) { float d = a0 - sx[base + 111]; lsum += (double)d * d; }
    if (sb + 1 <= 65478) { float d = a1 - sx[base + 112]; lsum += (double)d * d; }
    if (sb + 2 <= 65478) { float d = a2 - sx[base + 113]; lsum += (double)d * d; }
    if (sb + 3 <= 65478) { float d = a3 - sx[base + 114]; lsum += (double)d * d; }
    for (int off = 32; off > 0; off >>= 1) lsum += __shfl_down(lsum, off, 64);
    int w = tid >> 6;
    if ((tid & 63) == 0) wred[w] = lsum;
    __syncthreads();
    if (tid == 0)
        part[row * 64 + blockIdx.x] = wred[0] + wred[1] + wred[2] + wred[3];
}

// ---------------- K4: edge g_xp evals + edge loss partials (no atomics) ----------------
__global__ __launch_bounds__(256) void k4_edge(
    const float* __restrict__ x, const float* __restrict__ A,
    double* __restrict__ part2)
{
    __shared__ float Al[112][113];
    __shared__ float xpw[240];
    __shared__ double wacc[4];
    int row = blockIdx.x >> 1;
    int side = blockIdx.x & 1;
    const float* xr = x + row * TLEN;
    int tid = threadIdx.x;

    for (int idx = tid; idx < 12544; idx += 256)
        Al[idx / 112][idx % 112] = A[idx];
    {
        int n_x = side ? 225 : 222;
        int woff0 = side ? 65423 : 0;
        if (tid < n_x) xpw[tid] = fetch_xp(xr, woff0 + tid);
    }
    __syncthreads();

    int w = tid >> 6, lane = tid & 63;
    int nS = side ? 57 : 56;
    int woff = side ? 65423 : 0;
    double lacc = 0.0;
    for (int s = w; s < nS; s += 4) {
        float part = 0.f;
#pragma unroll
        for (int half = 0; half < 2; ++half) {
            int i;
            bool has;
            if (!side) { i = half ? (54 - s) : (55 + s); has = half ? (s <= 54) : true; }
            else       { i = half ? (65647 - s) : (65534 + s); has = true; }
            if (has) {
                int klo = max(0, i - 65536);
                int khi = min(111, i);
                int k0 = klo + ((klo ^ i) & 1);
                for (int k = k0; k <= khi; k += 2) {
                    int bi = i - k - woff;
                    part = fmaf(xpw[bi + lane], Al[lane][k], part);
                    if (lane < 48)
                        part = fmaf(xpw[bi + 64 + lane], Al[lane + 64][k], part);
                }
            }
        }
        for (int off = 32; off > 0; off >>= 1) part += __shfl_down(part, off, 64);
        if (lane == 0) {
            float xs = xpw[side ? (111 + s) : (s + 55)];
            float diff = part - xs;
            lacc += (double)diff * diff;
        }
    }
    if (lane == 0) wacc[w] = lacc;
    __syncthreads();
    if (tid == 0) part2[blockIdx.x] = wacc[0] + wacc[1] + wacc[2] + wacc[3];
}

// ---------------- K5: final reduction ----------------
__global__ __launch_bounds__(256) void k5_final(
    const double* __restrict__ part, const double* __restrict__ part2,
    float* __restrict__ out_loss)
{
    __shared__ double red[256];
    double acc = 0.0;
    for (int idx = threadIdx.x; idx < 3072; idx += 256) acc += part[idx];
    if (threadIdx.x < 96) acc += part2[threadIdx.x];
    red[threadIdx.x] = acc;
    __syncthreads();
    for (int st = 128; st > 0; st >>= 1) {
        if (threadIdx.x < st) red[threadIdx.x] += red[threadIdx.x + st];
        __syncthreads();
    }
    if (threadIdx.x == 0)
        out_loss[0] = (float)(red[0] / 3145728.0);
}

// ---------------- launch ----------------
extern "C" void kernel_launch(void* const* d_in, const int* in_sizes, int n_in,
                              void* d_out, int out_size, void* d_ws, size_t ws_size,
                              hipStream_t stream)
{
    (void)in_sizes; (void)n_in; (void)ws_size;
    const float* x  = (const float*)d_in[0];
    const float* m  = (const float*)d_in[1];
    const float* p  = (const float*)d_in[2];
    const float* sd = (const float*)d_in[3];
    const float* kb = (const float*)d_in[4];
    float* out = (float*)d_out;
    float* ws  = (float*)d_ws;

    float* ws_w     = ws;            // 7168 : W[k][o] f32
    float* ws_C     = ws + 7168;     // 448  : C[q][224]
    float* ws_A     = ws + 7616;     // 12544: A[j][k] -> ends 20160
    double* ws_part  = (double*)(ws + 20160); // 3072 doubles -> ends 26304
    double* ws_part2 = (double*)(ws + 26304); // 96 doubles   -> ends 26496
    ushort* ws_wtb  = (ushort*)(ws + 26496);  // 8192 ushort: Wt[o][k] bf16 padded

    k1_filters<<<1, 256, 0, stream>>>(m, p, sd, kb, ws_w, ws_wtb);
    k1b_A<<<49, 256, 0, stream>>>(ws_w, ws_A);
    k1c_C<<<2, 256, 0, stream>>>(ws_A, ws_C);
    k2_fwd<<<dim3(16, 48), 256, 0, stream>>>(x, ws_wtb, out, out + OU_SIZE);
    k3_interior<<<dim3(64, 48), 256, 0, stream>>>(x, ws_C, ws_part);
    k4_edge<<<96, 256, 0, stream>>>(x, ws_A, ws_part2);
    k5_final<<<1, 256, 0, stream>>>(ws_part, ws_part2, out + (out_size - 1));
}

// Round 7
// 275.621 us; speedup vs baseline: 1.2773x; 1.1321x over previous
//
#include <hip/hip_runtime.h>

#define TLEN 65536
#define XPLEN 65648   /* TLEN + 112 padded length */
#define TO 32769
#define OU_SIZE 50333184   /* 16*32*3*32769 */

typedef __attribute__((ext_vector_type(8))) short short8v;
typedef __attribute__((ext_vector_type(4))) float float4v;

// ---------------- helpers ----------------
__device__ __forceinline__ float fetch_xp(const float* __restrict__ xr, int idx) {
    // xp[idx] for idx in [0, XPLEN) ; xp = symmetric-pad(x, 55 left, 57 right)
    int p = idx - 55;
    p = (p < 0) ? (-1 - p) : p;
    p = (p >= TLEN) ? (2 * TLEN - 1 - p) : p;
    return xr[p];
}

__device__ __forceinline__ ushort f2bf(float f) {
    unsigned u = __float_as_uint(f);
    unsigned r = (u + 0x7fffu + ((u >> 16) & 1u)) >> 16;
    return (ushort)r;
}

// ---------------- K1: filters ----------------
__global__ __launch_bounds__(256) void k1_filters(
    const float* __restrict__ m, const float* __restrict__ p,
    const float* __restrict__ sd, const float* __restrict__ kb,
    float* __restrict__ Wout, ushort* __restrict__ Wtb)
{
    __shared__ float knots[32][8];
    __shared__ float yh[2][6][4];
    __shared__ float fv[2][32][112];
    __shared__ float mx[64];
    __shared__ float mv[2][7], pv[2][7];
    int tid = threadIdx.x;
    if (tid < 32) {
        float s = exp2f((float)tid * 0.125f) + sd[tid];
        float cum = 0.f;
        for (int k = 0; k < 7; ++k) {
            float c = fminf(fmaxf(kb[k] * s, 1.f), 105.f);
            knots[tid][k] = cum - 3.f * s;   // exclusive cumsum - (K//2)*scale
            cum += c;
        }
    }
    if (tid < 2) {
        float mean = 0.f;
        for (int k = 1; k <= 5; ++k) mean += m[tid * 7 + k];
        mean *= 0.2f;
        for (int k = 0; k < 7; ++k) {
            float msk = (k == 0 || k == 6) ? 0.f : 1.f;
            mv[tid][k] = (m[tid * 7 + k] - mean) * msk;
            pv[tid][k] = p[tid * 7 + k] * msk;
        }
    }
    __syncthreads();
    if (tid < 12) {
        int i = tid / 6, kk = tid % 6;
        float y0 = mv[i][kk], y1 = mv[i][kk + 1], y2 = pv[i][kk], y3 = pv[i][kk + 1];
        yh[i][kk][0] = y0;
        yh[i][kk][1] = y1;
        yh[i][kk][2] = -3.f * y0 - 2.f * y1 + 3.f * y2 - y3;
        yh[i][kk][3] = 2.f * y0 + y1 - 2.f * y2 + y3;
    }
    __syncthreads();
    for (int idx = tid; idx < 7168; idx += 256) {
        int i = idx / 3584, s = (idx / 112) % 32, fi = idx % 112;
        float xi = -56.f + (float)fi * (112.f / 111.f);
        float val = 0.f;
        for (int kk = 0; kk < 6; ++kk) {
            float x0 = knots[s][kk], x1 = knots[s][kk + 1];
            float xn = (xi - x0) / (x1 - x0);
            if (xn >= 0.f && xn < 1.f) {
                val += ((yh[i][kk][3] * xn + yh[i][kk][2]) * xn + yh[i][kk][1]) * xn + yh[i][kk][0];
            }
        }
        fv[i][s][fi] = val;
    }
    __syncthreads();
    if (tid < 64) {
        int i = tid >> 5, s = tid & 31;
        float mm_ = -1e30f;
        for (int fi = 0; fi < 112; ++fi) mm_ = fmaxf(mm_, fv[i][s][fi]);
        mx[tid] = mm_;
    }
    __syncthreads();
    for (int idx = tid; idx < 7168; idx += 256) {
        int i = idx / 3584, s = (idx / 112) % 32, fi = idx % 112;
        int o = i * 32 + s;
        Wout[fi * 64 + o] = fv[i][s][fi] / mx[o];   // layout W[k][o] (f32, for A)
    }
    for (int idx = tid; idx < 8192; idx += 256) {
        int o = idx >> 7, k = idx & 127;
        float val = (k < 112) ? fv[o >> 5][o & 31][k] / mx[o] : 0.f;
        Wtb[idx] = f2bf(val);                      // layout Wt[o][k] bf16, K padded to 128
    }
}

// ---------------- K1b: A[j][k] = sum_o W[j,o] W[k,o] ----------------
__global__ __launch_bounds__(256) void k1b_A(const float* __restrict__ W, float* __restrict__ A)
{
    int idx = blockIdx.x * 256 + threadIdx.x;
    if (idx >= 12544) return;
    int j = idx / 112, k = idx % 112;
    float s = 0.f;
    for (int o = 0; o < 64; ++o) s += W[j * 64 + o] * W[k * 64 + o];
    A[idx] = s;
}

// ---------------- K1c: C[q][dd] ----------------
__global__ __launch_bounds__(256) void k1c_C(const float* __restrict__ A, float* __restrict__ C)
{
    int idx = blockIdx.x * 256 + threadIdx.x;
    if (idx >= 448) return;
    int q = idx / 224, dd = idx % 224;
    int d = dd - 111;
    float s = 0.f;
    for (int k = q; k < 112; k += 2) {
        int jj = k + d;
        if (jj >= 0 && jj < 112) s += A[jj * 112 + k];
    }
    C[idx] = s;
}

// ---------------- K2: persistent-W MFMA conv, consecutive tiles, flush||stage overlap ----------------
__global__ __launch_bounds__(256) void k2_fwd(
    const float* __restrict__ x, const ushort* __restrict__ Wtb,
    float* __restrict__ out_u, float* __restrict__ out_s)
{
    __shared__ __align__(16) ushort xraw[384];   // bf16 window xp[2*t0 .. 2*t0+383]
    __shared__ float ub[128][33];                // u values [t_local][sc]
    __shared__ float pb[32][33];                 // pooled values [sc][tp_local]
    int row = blockIdx.y;                 // n = b*3 + c
    int b = row / 3, c = row % 3;
    const float* xr = x + row * TLEN;
    int tid = threadIdx.x;
    int l = tid & 63, w = tid >> 6;
    int r16 = l & 15, kg = l >> 4;

    union U8 { short8v v; uint u[4]; uint4 q; };

    // hoist all B-operand fragments into registers once per block (16 KB table)
    const ushort* WB = Wtb + r16 * 128 + 8 * kg;
    U8 wreg[4][4];
#pragma unroll
    for (int n = 0; n < 4; ++n)
#pragma unroll
        for (int ks = 0; ks < 4; ++ks)
            wreg[n][ks].q = *(const uint4*)(WB + n * 2048 + 32 * ks);

    int ebase = 2 * (32 * w + r16) + 8 * kg;

    // consecutive tile range per block: sequential writes per output row
    int tstart = blockIdx.x * 16;
    int tend = (blockIdx.x == 15) ? 257 : (tstart + 16);
    int prev_t0 = -1;

    for (int tile = tstart; tile <= tend; ++tile) {
        int t0 = tile * 128;
        bool do_stage = (tile < tend);

        __syncthreads();   // ub/pb of prev tile complete; xraw consumers done
        if (do_stage) {
            for (int i = tid; i < 384; i += 256) {
                int idx = 2 * t0 + i;
                float v = (idx < XPLEN) ? fetch_xp(xr, idx) : 0.f;
                xraw[i] = f2bf(v);
            }
        }
        // flush previous tile's results while staging loads are in flight
        if (prev_t0 >= 0) {
            int col = tid & 127;
            int hrow = tid >> 7;             // 0 or 1
            int t = prev_t0 + col;
            bool tok = t < TO;
            size_t base0 = ((size_t)((b * 32) * 3 + c)) * TO + t;
#pragma unroll
            for (int rr = 0; rr < 16; ++rr) {
                int orow = 2 * rr + hrow;
                float v = ub[col][orow];
                if (tok) out_u[base0 + (size_t)orow * 3 * TO] = v;
            }
            int tp0 = prev_t0 >> 2;
#pragma unroll
            for (int rr = 0; rr < 4; ++rr) {
                int s2 = rr * 256 + tid;
                int orow2 = s2 >> 5, tpl = s2 & 31;
                if (tp0 + tpl < 8192)
                    out_s[((size_t)(row * 32 + orow2)) * 8192 + tp0 + tpl] = pb[orow2][tpl];
            }
        }
        if (!do_stage) break;
        __syncthreads();   // xraw ready; ub/pb free to overwrite

        float4v acc[2][4];
#pragma unroll
        for (int mt = 0; mt < 2; ++mt)
#pragma unroll
            for (int n = 0; n < 4; ++n)
                acc[mt][n] = (float4v){0.f, 0.f, 0.f, 0.f};

#pragma unroll
        for (int ks = 0; ks < 4; ++ks) {
            U8 a0, a1;
            int e0 = ebase + 32 * ks;
#pragma unroll
            for (int q = 0; q < 4; ++q) {
                a0.u[q] = *(const uint*)&xraw[e0 + 2 * q];        // mt=0 (t .. t+15)
                a1.u[q] = *(const uint*)&xraw[e0 + 32 + 2 * q];   // mt=1 (t+16 ..)
            }
#pragma unroll
            for (int n = 0; n < 4; ++n) {
                acc[0][n] = __builtin_amdgcn_mfma_f32_16x16x32_bf16(a0.v, wreg[n][ks].v, acc[0][n], 0, 0, 0);
                acc[1][n] = __builtin_amdgcn_mfma_f32_16x16x32_bf16(a1.v, wreg[n][ks].v, acc[1][n], 0, 0, 0);
            }
        }

        // lane holds: col o = n*16 + r16, rows t = tl + r ; re/im pairs (n=0,n=2) and (n=1,n=3)
#pragma unroll
        for (int mt = 0; mt < 2; ++mt) {
            int tl = 32 * w + 16 * mt + 4 * kg;
            float u1[4], u2[4];
#pragma unroll
            for (int r = 0; r < 4; ++r) {
                float re1 = acc[mt][0][r], im1 = acc[mt][2][r];
                float re2 = acc[mt][1][r], im2 = acc[mt][3][r];
                u1[r] = sqrtf(re1 * re1 + im1 * im1);
                u2[r] = sqrtf(re2 * re2 + im2 * im2);
            }
#pragma unroll
            for (int r = 0; r < 4; ++r) {
                ub[tl + r][r16]      = u1[r];
                ub[tl + r][r16 + 16] = u2[r];
            }
            pb[r16][tl >> 2]      = (u1[0] + u1[1] + u1[2] + u1[3]) * 0.25f;
            pb[r16 + 16][tl >> 2] = (u2[0] + u2[1] + u2[2] + u2[3]) * 0.25f;
        }
        prev_t0 = t0;
    }
}

// ---------------- K3: interior inverse + loss (C in LDS, no atomics) ----------------
__global__ __launch_bounds__(256) void k3_interior(
    const float* __restrict__ x, const float* __restrict__ C,
    double* __restrict__ part)
{
    __shared__ __align__(16) float sx[1248];
    __shared__ __align__(16) float Cl[448];
    __shared__ double wred[4];
    int row = blockIdx.y;
    int s0 = 56 + blockIdx.x * 1024;
    const float* xr = x + row * TLEN;
    int tid = threadIdx.x;
    for (int li = tid; li < 1248; li += 256) {
        int pp = s0 - 111 + li;
        pp = (pp < 0) ? (-1 - pp) : pp;
        pp = (pp >= TLEN) ? (2 * TLEN - 1 - pp) : pp;
        sx[li] = xr[pp];
    }
    for (int li = tid; li < 448; li += 256) Cl[li] = C[li];
    __syncthreads();

    int qe = (55 + s0) & 1;
    const float* Ce = Cl + qe * 224;
    const float* Co = Cl + (qe ^ 1) * 224;
    int base = tid * 4;
    float a0 = 0.f, a1 = 0.f, a2 = 0.f, a3 = 0.f;
    float4 cur = *(const float4*)&sx[base];
#pragma unroll 4
    for (int d4 = 0; d4 < 56; ++d4) {
        float4 nxt = *(const float4*)&sx[base + 4 * d4 + 4];
        float4 cev = *(const float4*)&Ce[4 * d4];     // LDS broadcast
        float4 cov = *(const float4*)&Co[4 * d4];     // LDS broadcast
        a0 = fmaf(cur.x, cev.x, a0); a1 = fmaf(cur.y, cov.x, a1); a2 = fmaf(cur.z, cev.x, a2); a3 = fmaf(cur.w, cov.x, a3);
        a0 = fmaf(cur.y, cev.y, a0); a1 = fmaf(cur.z, cov.y, a1); a2 = fmaf(cur.w, cev.y, a2); a3 = fmaf(nxt.x, cov.y, a3);
        a0 = fmaf(cur.z, cev.z, a0); a1 = fmaf(cur.w, cov.z, a1); a2 = fmaf(nxt.x, cev.z, a2); a3 = fmaf(nxt.y, cov.z, a3);
        a0 = fmaf(cur.w, cev.w, a0); a1 = fmaf(nxt.x, cov.w, a1); a2 = fmaf(nxt.y, cev.w, a2); a3 = fmaf(nxt.z, cov.w, a3);
        cur = nxt;
    }

    int sb = s0 + base;
    double lsum = 0.0;
    if (sb + 0 <= 65478) { float d = a0 - sx[base + 111]; lsum += (double)d * d; }
    if (sb + 1 <= 65478) { float d = a1 - sx[base + 112]; lsum += (double)d * d; }
    if (sb + 2 <= 65478) { float d = a2 - sx[base + 113]; lsum += (double)d * d; }
    if (sb + 3 <= 65478) { float d = a3 - sx[base + 114]; lsum += (double)d * d; }
    for (int off = 32; off > 0; off >>= 1) lsum += __shfl_down(lsum, off, 64);
    int w = tid >> 6;
    if ((tid & 63) == 0) wred[w] = lsum;
    __syncthreads();
    if (tid == 0)
        part[row * 64 + blockIdx.x] = wred[0] + wred[1] + wred[2] + wred[3];
}

// ---------------- K4: edge g_xp evals + edge loss partials (no atomics) ----------------
__global__ __launch_bounds__(256) void k4_edge(
    const float* __restrict__ x, const float* __restrict__ A,
    double* __restrict__ part2)
{
    __shared__ float Al[112][113];
    __shared__ float xpw[240];
    __shared__ double wacc[4];
    int row = blockIdx.x >> 1;
    int side = blockIdx.x & 1;
    const float* xr = x + row * TLEN;
    int tid = threadIdx.x;

    for (int idx = tid; idx < 12544; idx += 256)
        Al[idx / 112][idx % 112] = A[idx];
    {
        int n_x = side ? 225 : 222;
        int woff0 = side ? 65423 : 0;
        if (tid < n_x) xpw[tid] = fetch_xp(xr, woff0 + tid);
    }
    __syncthreads();

    int w = tid >> 6, lane = tid & 63;
    int nS = side ? 57 : 56;
    int woff = side ? 65423 : 0;
    double lacc = 0.0;
    for (int s = w; s < nS; s += 4) {
        float part = 0.f;
#pragma unroll
        for (int half = 0; half < 2; ++half) {
            int i;
            bool has;
            if (!side) { i = half ? (54 - s) : (55 + s); has = half ? (s <= 54) : true; }
            else       { i = half ? (65647 - s) : (65534 + s); has = true; }
            if (has) {
                int klo = max(0, i - 65536);
                int khi = min(111, i);
                int k0 = klo + ((klo ^ i) & 1);
                for (int k = k0; k <= khi; k += 2) {
                    int bi = i - k - woff;
                    part = fmaf(xpw[bi + lane], Al[lane][k], part);
                    if (lane < 48)
                        part = fmaf(xpw[bi + 64 + lane], Al[lane + 64][k], part);
                }
            }
        }
        for (int off = 32; off > 0; off >>= 1) part += __shfl_down(part, off, 64);
        if (lane == 0) {
            float xs = xpw[side ? (111 + s) : (s + 55)];
            float diff = part - xs;
            lacc += (double)diff * diff;
        }
    }
    if (lane == 0) wacc[w] = lacc;
    __syncthreads();
    if (tid == 0) part2[blockIdx.x] = wacc[0] + wacc[1] + wacc[2] + wacc[3];
}

// ---------------- K5: final reduction ----------------
__global__ __launch_bounds__(256) void k5_final(
    const double* __restrict__ part, const double* __restrict__ part2,
    float* __restrict__ out_loss)
{
    __shared__ double red[256];
    double acc = 0.0;
    for (int idx = threadIdx.x; idx < 3072; idx += 256) acc += part[idx];
    if (threadIdx.x < 96) acc += part2[threadIdx.x];
    red[threadIdx.x] = acc;
    __syncthreads();
    for (int st = 128; st > 0; st >>= 1) {
        if (threadIdx.x < st) red[threadIdx.x] += red[threadIdx.x + st];
        __syncthreads();
    }
    if (threadIdx.x == 0)
        out_loss[0] = (float)(red[0] / 3145728.0);
}

// ---------------- launch ----------------
extern "C" void kernel_launch(void* const* d_in, const int* in_sizes, int n_in,
                              void* d_out, int out_size, void* d_ws, size_t ws_size,
                              hipStream_t stream)
{
    (void)in_sizes; (void)n_in; (void)ws_size;
    const float* x  = (const float*)d_in[0];
    const float* m  = (const float*)d_in[1];
    const float* p  = (const float*)d_in[2];
    const float* sd = (const float*)d_in[3];
    const float* kb = (const float*)d_in[4];
    float* out = (float*)d_out;
    float* ws  = (float*)d_ws;

    float* ws_w     = ws;            // 7168 : W[k][o] f32
    float* ws_C     = ws + 7168;     // 448  : C[q][224]
    float* ws_A     = ws + 7616;     // 12544: A[j][k] -> ends 20160
    double* ws_part  = (double*)(ws + 20160); // 3072 doubles -> ends 26304
    double* ws_part2 = (double*)(ws + 26304); // 96 doubles   -> ends 26496
    ushort* ws_wtb  = (ushort*)(ws + 26496);  // 8192 ushort: Wt[o][k] bf16 padded

    k1_filters<<<1, 256, 0, stream>>>(m, p, sd, kb, ws_w, ws_wtb);
    k1b_A<<<49, 256, 0, stream>>>(ws_w, ws_A);
    k1c_C<<<2, 256, 0, stream>>>(ws_A, ws_C);
    k2_fwd<<<dim3(16, 48), 256, 0, stream>>>(x, ws_wtb, out, out + OU_SIZE);
    k3_interior<<<dim3(64, 48), 256, 0, stream>>>(x, ws_C, ws_part);
    k4_edge<<<96, 256, 0, stream>>>(x, ws_A, ws_part2);
    k5_final<<<1, 256, 0, stream>>>(ws_part, ws_part2, out + (out_size - 1));
}